// Round 2
// baseline (913.906 us; speedup 1.0000x reference)
//
#include <hip/hip_runtime.h>
#include <hip/hip_bf16.h>

// SMPL-X LBS forward. B=512, V=10475, J=55. All tensors float32 per reference.

#define VN   10475
#define JN   55
#define BN   512
#define KPD  486            // (J-1)*9 pose-feature length
#define VC3  (VN*3)         // 31425

// ---- workspace layout (float units) ----
#define S_OFF     0         // s_dirs: v_template + shape*shapedirs, VC3 floats
#define JS_OFF    31425     // Js[j][c]:  J_reg @ s_dirs, 165 floats
#define JE_OFF    31590     // JE[j][c][e]: J_reg @ exprdirs, 1650 floats
#define Y_OFF     33240     // y_offset scalar
#define PF_OFF    33248     // pose_feature, B rows x 488 (padded for float4)
#define PF_STRIDE 488
#define A_OFF     283104    // A[b][j][12], B*660 floats  (total ws ~2.5 MB)

// ---------------- kernel 1: s_dirs = v_template + shape . shapedirs ----------
__global__ void k_sdirs(const float* __restrict__ vt, const float* __restrict__ shapedirs,
                        const float* __restrict__ shape, float* __restrict__ ws)
{
    int i = blockIdx.x * 256 + threadIdx.x;
    if (i >= VC3) return;
    float acc = vt[i];
    const float* sd = shapedirs + (size_t)i * 10;   // layout (V,3,10)
    #pragma unroll
    for (int s = 0; s < 10; ++s) acc += shape[s] * sd[s];
    ws[S_OFF + i] = acc;
}

// ---------------- kernel 2: y_offset = -min(v_template[:,1]) ----------------
__global__ void k_ymin(const float* __restrict__ vt, float* __restrict__ ws)
{
    __shared__ float red[256];
    int tid = threadIdx.x;
    float m = 3.0e38f;
    for (int v = tid; v < VN; v += 256) m = fminf(m, vt[v*3 + 1]);
    red[tid] = m;
    __syncthreads();
    for (int s = 128; s > 0; s >>= 1) {
        if (tid < s) red[tid] = fminf(red[tid], red[tid + s]);
        __syncthreads();
    }
    if (tid == 0) ws[Y_OFF] = -red[0];
}

// ------- kernel 3: Js = J_reg @ s_dirs ; JE = J_reg @ exprdirs  (per (j,c)) --
__global__ void k_jreg(const float* __restrict__ jr, const float* __restrict__ exprdirs,
                       float* __restrict__ ws)
{
    int j = blockIdx.x / 3, c = blockIdx.x % 3;
    int tid = threadIdx.x;
    const float* sdir = ws + S_OFF;
    float acc[11];
    #pragma unroll
    for (int i = 0; i < 11; ++i) acc[i] = 0.f;
    for (int v = tid; v < VN; v += 256) {
        float w = jr[(size_t)j * VN + v];
        acc[10] += w * sdir[v*3 + c];
        const float* ed = exprdirs + (size_t)(v*3 + c) * 10;
        #pragma unroll
        for (int e = 0; e < 10; ++e) acc[e] += w * ed[e];
    }
    __shared__ float red[256];
    for (int i = 0; i < 11; ++i) {
        red[tid] = acc[i];
        __syncthreads();
        for (int s = 128; s > 0; s >>= 1) {
            if (tid < s) red[tid] += red[tid + s];
            __syncthreads();
        }
        if (tid == 0) {
            if (i == 10) ws[JS_OFF + j*3 + c] = red[0];
            else         ws[JE_OFF + (j*3 + c)*10 + i] = red[0];
        }
        __syncthreads();
    }
}

// ---- kernel 4: per-batch Rodrigues, pose_feature, joints, kinematic chain, A
// one block (64 threads = 1 wave) per batch
__global__ void k_batch(const float* __restrict__ body, const float* __restrict__ hand,
                        const float* __restrict__ head, const float* __restrict__ expr,
                        const float* __restrict__ pelvis, const float* __restrict__ hand_mean,
                        float* __restrict__ ws)
{
    int b = blockIdx.x, tid = threadIdx.x;
    __shared__ float rot[JN][9];
    __shared__ float jnt[JN][3];
    __shared__ float G[12];

    if (tid < JN) {
        int j = tid;
        float r0, r1, r2;
        if (j == 0) {
            r0 = pelvis[b*3+0]; r1 = pelvis[b*3+1]; r2 = pelvis[b*3+2];
        } else if (j <= 21) {
            int o = b*63 + (j-1)*3;
            r0 = body[o]; r1 = body[o+1]; r2 = body[o+2];
        } else if (j <= 24) {
            int o = b*9 + (j-22)*3;
            r0 = head[o]; r1 = head[o+1]; r2 = head[o+2];
        } else {
            int h = (j-25)*3;
            r0 = hand[b*90+h+0] + hand_mean[h+0];
            r1 = hand[b*90+h+1] + hand_mean[h+1];
            r2 = hand[b*90+h+2] + hand_mean[h+2];
        }
        // Rodrigues: R = cI + s K + (1-c) kk^T
        float a2  = r0*r0 + r1*r1 + r2*r2 + 1e-12f;
        float ang = sqrtf(a2);
        float inv = 1.0f / ang;
        float kx = r0*inv, ky = r1*inv, kz = r2*inv;
        float s = sinf(ang), c = cosf(ang), ic = 1.0f - c;
        rot[j][0] = c + ic*kx*kx;    rot[j][1] = ic*kx*ky - s*kz; rot[j][2] = ic*kx*kz + s*ky;
        rot[j][3] = ic*kx*ky + s*kz; rot[j][4] = c + ic*ky*ky;    rot[j][5] = ic*ky*kz - s*kx;
        rot[j][6] = ic*kx*kz - s*ky; rot[j][7] = ic*ky*kz + s*kx; rot[j][8] = c + ic*kz*kz;
        // joints[b][j][c] = Js + expr . JE
        #pragma unroll
        for (int cc = 0; cc < 3; ++cc) {
            float acc = ws[JS_OFF + j*3 + cc];
            #pragma unroll
            for (int e = 0; e < 10; ++e)
                acc += expr[b*10 + e] * ws[JE_OFF + (j*3 + cc)*10 + e];
            jnt[j][cc] = acc;
        }
    }
    __syncthreads();

    // pose_feature = rotmats[1:] - I
    for (int idx = tid; idx < KPD; idx += 64) {
        int jj = idx / 9 + 1, i = idx % 9;
        float d = (i == 0 || i == 4 || i == 8) ? 1.0f : 0.0f;
        ws[PF_OFF + (size_t)b*PF_STRIDE + idx] = rot[jj][i] - d;
    }

    // kinematic chain (parent of j is j-1): 12 lanes compute G (3x4)
    int r = tid >> 2, cc = tid & 3;
    if (tid < 12) G[tid] = (cc < 3) ? rot[0][r*3 + cc] : jnt[0][r];
    __syncthreads();
    float* A = ws + A_OFF + (size_t)b * 660;
    for (int j = 0; j < JN; ++j) {
        float tmp = 0.f;
        if (tid < 12) {
            if (j == 0) tmp = G[tid];
            else if (cc < 3)
                tmp = G[r*4+0]*rot[j][cc] + G[r*4+1]*rot[j][3+cc] + G[r*4+2]*rot[j][6+cc];
            else {
                float l0 = jnt[j][0]-jnt[j-1][0], l1 = jnt[j][1]-jnt[j-1][1], l2 = jnt[j][2]-jnt[j-1][2];
                tmp = G[r*4+0]*l0 + G[r*4+1]*l1 + G[r*4+2]*l2 + G[r*4+3];
            }
        }
        __syncthreads();
        if (tid < 12) G[tid] = tmp;
        __syncthreads();
        if (tid < 12) {
            float aval = tmp;
            if (cc == 3)   // A.t = G.t - G.R @ joints[j]
                aval = tmp - (G[r*4+0]*jnt[j][0] + G[r*4+1]*jnt[j][1] + G[r*4+2]*jnt[j][2]);
            A[j*12 + tid] = aval;
        }
        __syncthreads();
    }
}

// ---- kernel 5: fused v_shaped + posedirs + LBS + transform ----
// one thread = one vertex x 8 batches; pf/A read via wave-uniform addresses
__global__ __launch_bounds__(256) void k_fused(
    const float* __restrict__ posedirs, const float* __restrict__ exprdirs,
    const float* __restrict__ lbsw, const float* __restrict__ expr,
    const float* __restrict__ gtrans, const float* __restrict__ ws,
    float* __restrict__ out)
{
    int tid = threadIdx.x;
    int v   = blockIdx.x * 256 + tid;
    bool act = v < VN;
    int vv  = act ? v : VN - 1;
    int bg  = blockIdx.y;           // batch group of 8

    float yoff = ws[Y_OFF];

    float vp[8][3];
    {   // v_shaped = s_dirs + expr . exprdirs
        float s0 = ws[S_OFF + vv*3+0], s1 = ws[S_OFF + vv*3+1], s2 = ws[S_OFF + vv*3+2];
        const float* edp = exprdirs + (size_t)vv * 30;   // (V,3,10): 30 contiguous
        float ed[30];
        #pragma unroll
        for (int i = 0; i < 30; ++i) ed[i] = edp[i];
        #pragma unroll
        for (int bb = 0; bb < 8; ++bb) {
            const float* ex = expr + (size_t)(bg*8 + bb) * 10;
            float a0 = s0, a1 = s1, a2 = s2;
            #pragma unroll
            for (int e = 0; e < 10; ++e) {
                float xe = ex[e];
                a0 += xe * ed[e]; a1 += xe * ed[10+e]; a2 += xe * ed[20+e];
            }
            vp[bb][0] = a0; vp[bb][1] = a1; vp[bb][2] = a2;
        }
    }

    {   // v_posed += pose_feature @ posedirs  (k unrolled x4, float4 pf reads)
        const float*  pd  = posedirs + (size_t)vv * 3;
        const float4* pfg = (const float4*)(ws + PF_OFF + (size_t)(bg*8) * PF_STRIDE);
        for (int k4 = 0; k4 < 121; ++k4) {            // k = 0..483
            float p[4][3];
            #pragma unroll
            for (int kk = 0; kk < 4; ++kk) {
                const float* row = pd + (size_t)(k4*4 + kk) * VC3;
                p[kk][0] = row[0]; p[kk][1] = row[1]; p[kk][2] = row[2];
            }
            #pragma unroll
            for (int bb = 0; bb < 8; ++bb) {
                float4 f = pfg[bb * (PF_STRIDE/4) + k4];
                vp[bb][0] += f.x*p[0][0] + f.y*p[1][0] + f.z*p[2][0] + f.w*p[3][0];
                vp[bb][1] += f.x*p[0][1] + f.y*p[1][1] + f.z*p[2][1] + f.w*p[3][1];
                vp[bb][2] += f.x*p[0][2] + f.y*p[1][2] + f.z*p[2][2] + f.w*p[3][2];
            }
        }
        const float* pff = ws + PF_OFF + (size_t)(bg*8) * PF_STRIDE;
        for (int k = 484; k < 486; ++k) {             // tail
            const float* row = pd + (size_t)k * VC3;
            float p0 = row[0], p1 = row[1], p2 = row[2];
            #pragma unroll
            for (int bb = 0; bb < 8; ++bb) {
                float f = pff[bb*PF_STRIDE + k];
                vp[bb][0] += f*p0; vp[bb][1] += f*p1; vp[bb][2] += f*p2;
            }
        }
    }

    // LBS: T = sum_j w[v,j] * A[b,j] ; verts = T.R @ v_posed + T.t + yoff + gt
    const float* wp = lbsw + (size_t)vv * 55;
    #pragma unroll 1
    for (int bb = 0; bb < 8; ++bb) {
        int b = bg*8 + bb;
        const float4* Ab = (const float4*)(ws + A_OFF + (size_t)b * 660);
        float T[12];
        #pragma unroll
        for (int i = 0; i < 12; ++i) T[i] = 0.f;
        for (int j = 0; j < 55; ++j) {
            float wj = wp[j];
            float4 a0 = Ab[j*3+0], a1 = Ab[j*3+1], a2 = Ab[j*3+2];
            T[0]+=wj*a0.x; T[1]+=wj*a0.y; T[2] +=wj*a0.z; T[3] +=wj*a0.w;
            T[4]+=wj*a1.x; T[5]+=wj*a1.y; T[6] +=wj*a1.z; T[7] +=wj*a1.w;
            T[8]+=wj*a2.x; T[9]+=wj*a2.y; T[10]+=wj*a2.z; T[11]+=wj*a2.w;
        }
        float x = vp[bb][0], y = vp[bb][1], z = vp[bb][2];
        float ox = T[0]*x + T[1]*y + T[2] *z + T[3]         + gtrans[b*3+0];
        float oy = T[4]*x + T[5]*y + T[6] *z + T[7]  + yoff + gtrans[b*3+1];
        float oz = T[8]*x + T[9]*y + T[10]*z + T[11]        + gtrans[b*3+2];
        if (act) {
            size_t o = ((size_t)b * VN + v) * 3;
            out[o+0] = ox;
            out[o+1] = oy;
            out[o+2] = oz;
        }
    }
}

extern "C" void kernel_launch(void* const* d_in, const int* in_sizes, int n_in,
                              void* d_out, int out_size, void* d_ws, size_t ws_size,
                              hipStream_t stream)
{
    const float* shape  = (const float*)d_in[0];
    const float* body   = (const float*)d_in[1];
    const float* hand   = (const float*)d_in[2];
    const float* head   = (const float*)d_in[3];
    const float* expr   = (const float*)d_in[4];
    const float* pelvis = (const float*)d_in[5];
    const float* gtrans = (const float*)d_in[6];
    const float* vt     = (const float*)d_in[7];
    const float* shdirs = (const float*)d_in[8];
    const float* exdirs = (const float*)d_in[9];
    const float* pdirs  = (const float*)d_in[10];
    const float* lbsw   = (const float*)d_in[11];
    const float* jreg   = (const float*)d_in[12];
    const float* hmean  = (const float*)d_in[13];
    float* ws  = (float*)d_ws;
    float* out = (float*)d_out;

    hipLaunchKernelGGL(k_sdirs, dim3((VC3 + 255)/256), dim3(256), 0, stream,
                       vt, shdirs, shape, ws);
    hipLaunchKernelGGL(k_ymin,  dim3(1),   dim3(256), 0, stream, vt, ws);
    hipLaunchKernelGGL(k_jreg,  dim3(JN*3), dim3(256), 0, stream, jreg, exdirs, ws);
    hipLaunchKernelGGL(k_batch, dim3(BN),  dim3(64),  0, stream,
                       body, hand, head, expr, pelvis, hmean, ws);
    hipLaunchKernelGGL(k_fused, dim3((VN + 255)/256, BN/8), dim3(256), 0, stream,
                       pdirs, exdirs, lbsw, expr, gtrans, ws, out);
}

// Round 3
// 377.748 us; speedup vs baseline: 2.4194x; 2.4194x over previous
//
#include <hip/hip_runtime.h>
#include <hip/hip_bf16.h>

// SMPL-X LBS forward. B=512, V=10475, J=55. f32 in/out; fp16 MFMA internally.
//
// Pipeline:
//  k_sdirs : s_dirs = v_template + shape.shapedirs            (f32, ws)
//  k_ymin  : y_offset = -min(vt[:,1])                          (f32, ws)
//  k_jreg  : Js = Jreg@s_dirs, JE = Jreg@exprdirs              (f32, ws)
//  k_batch : Rodrigues -> PFH fp16 [512][512] (pf | expr | 0 pad),
//            joints, kinematic chain -> AH fp16 [8192][64]
//            (row m = b*16 + r*4 + c, col k = joint j; zero padded)
//  k_pose  : MFMA GEMM  VP = PFH @ B,  B[k][n] = posedirs (k<486) |
//            exprdirs (486..495) | 0 ; epilogue += s_dirs -> VPH fp16
//  k_lbs   : MFMA GEMM  T = AH @ w^T ; epilogue out = T.[vp;1] + gt + yoff

typedef _Float16 f16;
typedef f16  f16x8 __attribute__((ext_vector_type(8)));
typedef float f32x4 __attribute__((ext_vector_type(4)));

#define VN    10475
#define JN    55
#define BN    512
#define VC3   31425
#define NPAD  31488          // 492*64 = 3*10496
#define VPADV 10496
#define VPROW (VPADV*4)      // halves per batch row of VPH (xyz + pad)

// ---- ws layout ----
// f32 region (float offsets):
#define SD_F  0              // s_dirs [VC3]
#define JS_F  31425          // [55*3]
#define JE_F  31590          // [55*3*10]
#define Y_F   33240          // scalar
// byte offsets (16B-aligned):
#define PFH_BYTE (160*1024)          // f16 [512][512]   = 512 KB
#define AH_BYTE  (768*1024)          // f16 [8192][64]   = 1 MB
#define VPH_BYTE (2*1024*1024)       // f16 [512][VPROW] = 43 MB  (total ~45 MB)

// ---------------- kernel 1: s_dirs ----------------
__global__ void k_sdirs(const float* __restrict__ vt, const float* __restrict__ shapedirs,
                        const float* __restrict__ shape, float* __restrict__ ws)
{
    int i = blockIdx.x * 256 + threadIdx.x;
    if (i >= VC3) return;
    float acc = vt[i];
    const float* sd = shapedirs + (size_t)i * 10;
    #pragma unroll
    for (int s = 0; s < 10; ++s) acc += shape[s] * sd[s];
    ws[SD_F + i] = acc;
}

// ---------------- kernel 2: y_offset ----------------
__global__ void k_ymin(const float* __restrict__ vt, float* __restrict__ ws)
{
    __shared__ float red[256];
    int tid = threadIdx.x;
    float m = 3.0e38f;
    for (int v = tid; v < VN; v += 256) m = fminf(m, vt[v*3 + 1]);
    red[tid] = m;
    __syncthreads();
    for (int s = 128; s > 0; s >>= 1) {
        if (tid < s) red[tid] = fminf(red[tid], red[tid + s]);
        __syncthreads();
    }
    if (tid == 0) ws[Y_F] = -red[0];
}

// ---------------- kernel 3: joint regressors ----------------
__global__ void k_jreg(const float* __restrict__ jr, const float* __restrict__ exprdirs,
                       float* __restrict__ ws)
{
    int j = blockIdx.x / 3, c = blockIdx.x % 3;
    int tid = threadIdx.x;
    const float* sdir = ws + SD_F;
    float acc[11];
    #pragma unroll
    for (int i = 0; i < 11; ++i) acc[i] = 0.f;
    for (int v = tid; v < VN; v += 256) {
        float w = jr[(size_t)j * VN + v];
        acc[10] += w * sdir[v*3 + c];
        const float* ed = exprdirs + (size_t)(v*3 + c) * 10;
        #pragma unroll
        for (int e = 0; e < 10; ++e) acc[e] += w * ed[e];
    }
    __shared__ float red[256];
    for (int i = 0; i < 11; ++i) {
        red[tid] = acc[i];
        __syncthreads();
        for (int s = 128; s > 0; s >>= 1) {
            if (tid < s) red[tid] += red[tid + s];
            __syncthreads();
        }
        if (tid == 0) {
            if (i == 10) ws[JS_F + j*3 + c] = red[0];
            else         ws[JE_F + (j*3 + c)*10 + i] = red[0];
        }
        __syncthreads();
    }
}

// ---------------- kernel 4: per-batch pose prep ----------------
// one wave per batch: Rodrigues, PFH row, joints, chain -> AH
__global__ void k_batch(const float* __restrict__ body, const float* __restrict__ hand,
                        const float* __restrict__ head, const float* __restrict__ expr,
                        const float* __restrict__ pelvis, const float* __restrict__ hand_mean,
                        const float* __restrict__ ws, f16* __restrict__ PFH,
                        f16* __restrict__ AH)
{
    int b = blockIdx.x, tid = threadIdx.x;
    __shared__ float rot[JN][9];
    __shared__ float jnt[JN][3];
    __shared__ float G[12];

    f16* AHb = AH + (size_t)b * 1024;          // 16 rows x 64 cols
    #pragma unroll
    for (int i = 0; i < 16; ++i) AHb[tid + i*64] = (f16)0.f;   // zero pad rows/cols

    if (tid < JN) {
        int j = tid;
        float r0, r1, r2;
        if (j == 0) {
            r0 = pelvis[b*3+0]; r1 = pelvis[b*3+1]; r2 = pelvis[b*3+2];
        } else if (j <= 21) {
            int o = b*63 + (j-1)*3;
            r0 = body[o]; r1 = body[o+1]; r2 = body[o+2];
        } else if (j <= 24) {
            int o = b*9 + (j-22)*3;
            r0 = head[o]; r1 = head[o+1]; r2 = head[o+2];
        } else {
            int h = (j-25)*3;
            r0 = hand[b*90+h+0] + hand_mean[h+0];
            r1 = hand[b*90+h+1] + hand_mean[h+1];
            r2 = hand[b*90+h+2] + hand_mean[h+2];
        }
        float a2  = r0*r0 + r1*r1 + r2*r2 + 1e-12f;
        float ang = sqrtf(a2);
        float inv = 1.0f / ang;
        float kx = r0*inv, ky = r1*inv, kz = r2*inv;
        float s = sinf(ang), c = cosf(ang), ic = 1.0f - c;
        rot[j][0] = c + ic*kx*kx;    rot[j][1] = ic*kx*ky - s*kz; rot[j][2] = ic*kx*kz + s*ky;
        rot[j][3] = ic*kx*ky + s*kz; rot[j][4] = c + ic*ky*ky;    rot[j][5] = ic*ky*kz - s*kx;
        rot[j][6] = ic*kx*kz - s*ky; rot[j][7] = ic*ky*kz + s*kx; rot[j][8] = c + ic*kz*kz;
        #pragma unroll
        for (int cc = 0; cc < 3; ++cc) {
            float acc = ws[JS_F + j*3 + cc];
            #pragma unroll
            for (int e = 0; e < 10; ++e)
                acc += expr[b*10 + e] * ws[JE_F + (j*3 + cc)*10 + e];
            jnt[j][cc] = acc;
        }
    }
    __syncthreads();

    // PFH row b: [0..486) pose_feature | [486..496) expr | [496..512) zero
    #pragma unroll
    for (int i = 0; i < 8; ++i) {
        int k = tid + i*64;
        float val = 0.f;
        if (k < 486) {
            int jj = k/9 + 1, ii = k%9;
            float d = (ii == 0 || ii == 4 || ii == 8) ? 1.0f : 0.0f;
            val = rot[jj][ii] - d;
        } else if (k < 496) {
            val = expr[b*10 + (k-486)];
        }
        PFH[(size_t)b*512 + k] = (f16)val;
    }

    // kinematic chain: 12 lanes hold G (3x4)
    int r = tid >> 2, cc = tid & 3;
    if (tid < 12) G[tid] = (cc < 3) ? rot[0][r*3 + cc] : jnt[0][r];
    __syncthreads();
    for (int j = 0; j < JN; ++j) {
        float tmp = 0.f;
        if (tid < 12) {
            if (j == 0) tmp = G[tid];
            else if (cc < 3)
                tmp = G[r*4+0]*rot[j][cc] + G[r*4+1]*rot[j][3+cc] + G[r*4+2]*rot[j][6+cc];
            else {
                float l0 = jnt[j][0]-jnt[j-1][0], l1 = jnt[j][1]-jnt[j-1][1], l2 = jnt[j][2]-jnt[j-1][2];
                tmp = G[r*4+0]*l0 + G[r*4+1]*l1 + G[r*4+2]*l2 + G[r*4+3];
            }
        }
        __syncthreads();
        if (tid < 12) G[tid] = tmp;
        __syncthreads();
        if (tid < 12) {
            float aval = tmp;
            if (cc == 3)
                aval = tmp - (G[r*4+0]*jnt[j][0] + G[r*4+1]*jnt[j][1] + G[r*4+2]*jnt[j][2]);
            AHb[tid*64 + j] = (f16)aval;   // row m = b*16 + (r*4+c), col j
        }
        __syncthreads();
    }
}

// ---------------- kernel 5: pose GEMM (MFMA) ----------------
// C[512 x 64n] per block; 4 waves, wave w owns 128 M-rows x 64 N-cols.
__global__ __launch_bounds__(256, 2) void k_pose(
    const float* __restrict__ pd, const float* __restrict__ ed,
    const float* __restrict__ ws, const f16* __restrict__ PFH,
    f16* __restrict__ VPH)
{
    __shared__ f16 Al[512*40];   // [m][k] k-contig, stride 40 halves
    __shared__ f16 Bl[64*40];    // [n][k]
    __shared__ float SDl[64];
    const int t = threadIdx.x;
    const int n0 = blockIdx.x * 64;
    const int w = t >> 6, lane = t & 63, l = lane & 15, q = lane >> 4;

    f32x4 acc[8][4];
    #pragma unroll
    for (int i = 0; i < 8; ++i)
        #pragma unroll
        for (int j = 0; j < 4; ++j) acc[i][j] = (f32x4)0.f;

    const int kkB = t >> 3;          // 0..31
    const int nnB = (t & 7) * 8;     // 0,8,..,56

    for (int kc = 0; kc < 16; ++kc) {
        __syncthreads();
        {   // stage A: PFH rows t and t+256, 32 halves each
            const uint4* s0 = (const uint4*)(PFH + (size_t)t*512 + kc*32);
            const uint4* s1 = (const uint4*)(PFH + (size_t)(t+256)*512 + kc*32);
            uint4* d0 = (uint4*)&Al[t*40];
            uint4* d1 = (uint4*)&Al[(t+256)*40];
            #pragma unroll
            for (int j = 0; j < 4; ++j) d0[j] = s0[j];
            #pragma unroll
            for (int j = 0; j < 4; ++j) d1[j] = s1[j];
        }
        {   // stage B transposed: B[k][n] -> Bl[n][k]
            int k = kc*32 + kkB;
            #pragma unroll
            for (int i = 0; i < 8; ++i) {
                int n = n0 + nnB + i;
                float v = 0.f;
                if (n < VC3) {
                    if (k < 486)      v = pd[(size_t)k*VC3 + n];
                    else if (k < 496) v = ed[(size_t)n*10 + (k-486)];
                }
                Bl[(nnB+i)*40 + kkB] = (f16)v;
            }
        }
        __syncthreads();
        f16x8 bf[4], af[8];
        #pragma unroll
        for (int nt = 0; nt < 4; ++nt)
            bf[nt] = *(const f16x8*)&Bl[(nt*16 + l)*40 + q*8];
        #pragma unroll
        for (int mt = 0; mt < 8; ++mt)
            af[mt] = *(const f16x8*)&Al[(w*128 + mt*16 + l)*40 + q*8];
        #pragma unroll
        for (int mt = 0; mt < 8; ++mt)
            #pragma unroll
            for (int nt = 0; nt < 4; ++nt)
                acc[mt][nt] = __builtin_amdgcn_mfma_f32_16x16x32_f16(af[mt], bf[nt], acc[mt][nt], 0, 0, 0);
    }

    if (t < 64) { int n = n0 + t; SDl[t] = (n < VC3) ? ws[SD_F + n] : 0.f; }
    __syncthreads();

    // epilogue: VPH[b][v*4+c] = C + s_dirs
    #pragma unroll
    for (int nt = 0; nt < 4; ++nt) {
        int nl = nt*16 + l, n = n0 + nl;
        int v = n / 3, c = n - v*3;
        float sd = SDl[nl];
        size_t base = (size_t)v*4 + c;
        #pragma unroll
        for (int mt = 0; mt < 8; ++mt) {
            int b0 = w*128 + mt*16 + q*4;
            #pragma unroll
            for (int i = 0; i < 4; ++i) {
                float val = acc[mt][nt][i] + sd;
                VPH[(size_t)(b0 + i)*VPROW + base] = (f16)val;
            }
        }
    }
}

// ---------------- kernel 6: LBS GEMM (MFMA) + epilogue ----------------
// T[(b*16+r*4+c), v] = AH @ w^T ; out[b,v,r] = T.[vp;1] + gt + yoff
__global__ __launch_bounds__(256, 2) void k_lbs(
    const float* __restrict__ lw, const float* __restrict__ gt,
    const float* __restrict__ ws, const f16* __restrict__ AH,
    const f16* __restrict__ VPH, float* __restrict__ out)
{
    __shared__ f16 Al[256*72];   // [m][k], stride 72 halves (K=64 + pad)
    __shared__ f16 Bl[64*72];    // [n=v][k=j]
    const int t = threadIdx.x;
    const int n0 = blockIdx.x * 64;
    const int m0 = blockIdx.y * 256;
    const int w = t >> 6, lane = t & 63, l = lane & 15, q = lane >> 4;

    {   // stage A: AH row m0+t (64 halves = 128 B)
        const uint4* s = (const uint4*)(AH + (size_t)(m0 + t)*64);
        uint4* d = (uint4*)&Al[t*72];
        #pragma unroll
        for (int j = 0; j < 8; ++j) d[j] = s[j];
    }
    {   // stage B: lbsw[v][j] -> Bl[v-n0][j], zero pad j>=55 / v>=VN
        int vl = t >> 2, j0 = (t & 3)*16;
        int v = n0 + vl;
        #pragma unroll
        for (int jj = 0; jj < 16; ++jj) {
            int j = j0 + jj;
            float val = (j < JN && v < VN) ? lw[(size_t)v*JN + j] : 0.f;
            Bl[vl*72 + j] = (f16)val;
        }
    }
    __syncthreads();

    f32x4 acc[4][4];
    #pragma unroll
    for (int i = 0; i < 4; ++i)
        #pragma unroll
        for (int j = 0; j < 4; ++j) acc[i][j] = (f32x4)0.f;

    #pragma unroll
    for (int ks = 0; ks < 2; ++ks) {
        f16x8 af[4], bf[4];
        #pragma unroll
        for (int nt = 0; nt < 4; ++nt)
            bf[nt] = *(const f16x8*)&Bl[(nt*16 + l)*72 + ks*32 + q*8];
        #pragma unroll
        for (int mt = 0; mt < 4; ++mt)
            af[mt] = *(const f16x8*)&Al[(w*64 + mt*16 + l)*72 + ks*32 + q*8];
        #pragma unroll
        for (int mt = 0; mt < 4; ++mt)
            #pragma unroll
            for (int nt = 0; nt < 4; ++nt)
                acc[mt][nt] = __builtin_amdgcn_mfma_f32_16x16x32_f16(af[mt], bf[nt], acc[mt][nt], 0, 0, 0);
    }

    float yoff = ws[Y_F];
    if (q < 3) {
        #pragma unroll
        for (int mt = 0; mt < 4; ++mt) {
            int b = (m0 >> 4) + w*4 + mt;
            float add = gt[b*3 + q] + (q == 1 ? yoff : 0.f);
            #pragma unroll
            for (int nt = 0; nt < 4; ++nt) {
                int v = n0 + nt*16 + l;
                if (v < VN) {
                    const f16* vp = VPH + (size_t)b*VPROW + (size_t)v*4;
                    float vx = (float)vp[0], vy = (float)vp[1], vz = (float)vp[2];
                    f32x4 T = acc[mt][nt];
                    out[((size_t)b*VN + v)*3 + q] = T[0]*vx + T[1]*vy + T[2]*vz + T[3] + add;
                }
            }
        }
    }
}

extern "C" void kernel_launch(void* const* d_in, const int* in_sizes, int n_in,
                              void* d_out, int out_size, void* d_ws, size_t ws_size,
                              hipStream_t stream)
{
    const float* shape  = (const float*)d_in[0];
    const float* body   = (const float*)d_in[1];
    const float* hand   = (const float*)d_in[2];
    const float* head   = (const float*)d_in[3];
    const float* expr   = (const float*)d_in[4];
    const float* pelvis = (const float*)d_in[5];
    const float* gtrans = (const float*)d_in[6];
    const float* vt     = (const float*)d_in[7];
    const float* shdirs = (const float*)d_in[8];
    const float* exdirs = (const float*)d_in[9];
    const float* pdirs  = (const float*)d_in[10];
    const float* lbsw   = (const float*)d_in[11];
    const float* jreg   = (const float*)d_in[12];
    const float* hmean  = (const float*)d_in[13];
    float* wsf = (float*)d_ws;
    f16*   PFH = (f16*)((char*)d_ws + PFH_BYTE);
    f16*   AH  = (f16*)((char*)d_ws + AH_BYTE);
    f16*   VPH = (f16*)((char*)d_ws + VPH_BYTE);
    float* out = (float*)d_out;

    hipLaunchKernelGGL(k_sdirs, dim3((VC3 + 255)/256), dim3(256), 0, stream,
                       vt, shdirs, shape, wsf);
    hipLaunchKernelGGL(k_ymin,  dim3(1),    dim3(256), 0, stream, vt, wsf);
    hipLaunchKernelGGL(k_jreg,  dim3(JN*3), dim3(256), 0, stream, jreg, exdirs, wsf);
    hipLaunchKernelGGL(k_batch, dim3(BN),   dim3(64),  0, stream,
                       body, hand, head, expr, pelvis, hmean, wsf, PFH, AH);
    hipLaunchKernelGGL(k_pose,  dim3(NPAD/64), dim3(256), 0, stream,
                       pdirs, exdirs, wsf, PFH, VPH);
    hipLaunchKernelGGL(k_lbs,   dim3(VPADV/64, 8192/256), dim3(256), 0, stream,
                       lbsw, gtrans, wsf, AH, VPH, out);
}

// Round 4
// 361.324 us; speedup vs baseline: 2.5293x; 1.0455x over previous
//
#include <hip/hip_runtime.h>
#include <hip/hip_bf16.h>

// SMPL-X LBS forward. B=512, V=10475, J=55. f32 in/out; fp16 MFMA internally.
//
//  k_sdirs : s_dirs = v_template + shape.shapedirs (+ zero JS/JE)
//  k_ymin  : y_offset
//  k_jreg  : Js = Jreg@s_dirs, JE = Jreg@exprdirs
//  k_batch : Rodrigues -> PFH f16 [512 b][512 k], chain -> AH f16 [8192][64]
//  k_pose  : D[vcol][b] = pdT_tile(LDS) x PFH(direct L2 B-frags); +s_dirs -> VPH
//  k_lbs   : T = AH(direct L2 A-frags) x lbsw^T(LDS); out = T.[vp;1]

typedef _Float16 f16;
typedef f16  f16x8 __attribute__((ext_vector_type(8)));
typedef f16  f16x4 __attribute__((ext_vector_type(4)));
typedef float f32x4 __attribute__((ext_vector_type(4)));

#define VN    10475
#define JN    55
#define BN    512
#define VC3   31425
#define NPAD  31488          // 492*64
#define VPADV 10496
#define VPROW (VPADV*4)      // halves per batch row of VPH (xyz + pad)

// f32 ws region (float offsets):
#define SD_F  0              // s_dirs [VC3]
#define JS_F  31425          // [165]
#define JE_F  31590          // [1650]
#define Y_F   33240
// byte offsets:
#define PFH_BYTE (160*1024)          // f16 [512][512]
#define AH_BYTE  (768*1024)          // f16 [8192][64]
#define VPH_BYTE (2*1024*1024)       // f16 [512][VPROW] = 43 MB

// ---------------- kernel 1 ----------------
__global__ void k_sdirs(const float* __restrict__ vt, const float* __restrict__ shapedirs,
                        const float* __restrict__ shape, float* __restrict__ ws)
{
    int i = blockIdx.x * 256 + threadIdx.x;
    if (i >= VC3) return;
    float acc = vt[i];
    const float* sd = shapedirs + (size_t)i * 10;
    #pragma unroll
    for (int s = 0; s < 10; ++s) acc += shape[s] * sd[s];
    ws[SD_F + i] = acc;
}

// ---------------- kernel 2 ----------------
__global__ void k_ymin(const float* __restrict__ vt, float* __restrict__ ws)
{
    __shared__ float red[256];
    int tid = threadIdx.x;
    float m = 3.0e38f;
    for (int v = tid; v < VN; v += 256) m = fminf(m, vt[v*3 + 1]);
    red[tid] = m;
    __syncthreads();
    for (int s = 128; s > 0; s >>= 1) {
        if (tid < s) red[tid] = fminf(red[tid], red[tid + s]);
        __syncthreads();
    }
    if (tid == 0) ws[Y_F] = -red[0];
}

// ---------------- kernel 3 ----------------
__global__ void k_jreg(const float* __restrict__ jr, const float* __restrict__ exprdirs,
                       float* __restrict__ ws)
{
    int j = blockIdx.x / 3, c = blockIdx.x % 3;
    int tid = threadIdx.x;
    const float* sdir = ws + SD_F;
    float acc[11];
    #pragma unroll
    for (int i = 0; i < 11; ++i) acc[i] = 0.f;
    for (int v = tid; v < VN; v += 256) {
        float w = jr[(size_t)j * VN + v];
        acc[10] += w * sdir[v*3 + c];
        const float* ed = exprdirs + (size_t)(v*3 + c) * 10;
        #pragma unroll
        for (int e = 0; e < 10; ++e) acc[e] += w * ed[e];
    }
    __shared__ float red[256];
    for (int i = 0; i < 11; ++i) {
        red[tid] = acc[i];
        __syncthreads();
        for (int s = 128; s > 0; s >>= 1) {
            if (tid < s) red[tid] += red[tid + s];
            __syncthreads();
        }
        if (tid == 0) {
            if (i == 10) ws[JS_F + j*3 + c] = red[0];
            else         ws[JE_F + (j*3 + c)*10 + i] = red[0];
        }
        __syncthreads();
    }
}

// ---------------- kernel 4: per-batch pose prep ----------------
__global__ void k_batch(const float* __restrict__ body, const float* __restrict__ hand,
                        const float* __restrict__ head, const float* __restrict__ expr,
                        const float* __restrict__ pelvis, const float* __restrict__ hand_mean,
                        const float* __restrict__ ws, f16* __restrict__ PFH,
                        f16* __restrict__ AH)
{
    int b = blockIdx.x, tid = threadIdx.x;
    __shared__ float rot[JN][9];
    __shared__ float jnt[JN][3];
    __shared__ float G[12];

    f16* AHb = AH + (size_t)b * 1024;
    #pragma unroll
    for (int i = 0; i < 16; ++i) AHb[tid + i*64] = (f16)0.f;

    if (tid < JN) {
        int j = tid;
        float r0, r1, r2;
        if (j == 0) {
            r0 = pelvis[b*3+0]; r1 = pelvis[b*3+1]; r2 = pelvis[b*3+2];
        } else if (j <= 21) {
            int o = b*63 + (j-1)*3;
            r0 = body[o]; r1 = body[o+1]; r2 = body[o+2];
        } else if (j <= 24) {
            int o = b*9 + (j-22)*3;
            r0 = head[o]; r1 = head[o+1]; r2 = head[o+2];
        } else {
            int h = (j-25)*3;
            r0 = hand[b*90+h+0] + hand_mean[h+0];
            r1 = hand[b*90+h+1] + hand_mean[h+1];
            r2 = hand[b*90+h+2] + hand_mean[h+2];
        }
        float a2  = r0*r0 + r1*r1 + r2*r2 + 1e-12f;
        float ang = sqrtf(a2);
        float inv = 1.0f / ang;
        float kx = r0*inv, ky = r1*inv, kz = r2*inv;
        float s = sinf(ang), c = cosf(ang), ic = 1.0f - c;
        rot[j][0] = c + ic*kx*kx;    rot[j][1] = ic*kx*ky - s*kz; rot[j][2] = ic*kx*kz + s*ky;
        rot[j][3] = ic*kx*ky + s*kz; rot[j][4] = c + ic*ky*ky;    rot[j][5] = ic*ky*kz - s*kx;
        rot[j][6] = ic*kx*kz - s*ky; rot[j][7] = ic*ky*kz + s*kx; rot[j][8] = c + ic*kz*kz;
        #pragma unroll
        for (int cc = 0; cc < 3; ++cc) {
            float acc = ws[JS_F + j*3 + cc];
            #pragma unroll
            for (int e = 0; e < 10; ++e)
                acc += expr[b*10 + e] * ws[JE_F + (j*3 + cc)*10 + e];
            jnt[j][cc] = acc;
        }
    }
    __syncthreads();

    // PFH row b: [0..486) pose_feature | [486..496) expr | [496..512) zero
    #pragma unroll
    for (int i = 0; i < 8; ++i) {
        int k = tid + i*64;
        float val = 0.f;
        if (k < 486) {
            int jj = k/9 + 1, ii = k%9;
            float d = (ii == 0 || ii == 4 || ii == 8) ? 1.0f : 0.0f;
            val = rot[jj][ii] - d;
        } else if (k < 496) {
            val = expr[b*10 + (k-486)];
        }
        PFH[(size_t)b*512 + k] = (f16)val;
    }

    int r = tid >> 2, cc = tid & 3;
    if (tid < 12) G[tid] = (cc < 3) ? rot[0][r*3 + cc] : jnt[0][r];
    __syncthreads();
    for (int j = 0; j < JN; ++j) {
        float tmp = 0.f;
        if (tid < 12) {
            if (j == 0) tmp = G[tid];
            else if (cc < 3)
                tmp = G[r*4+0]*rot[j][cc] + G[r*4+1]*rot[j][3+cc] + G[r*4+2]*rot[j][6+cc];
            else {
                float l0 = jnt[j][0]-jnt[j-1][0], l1 = jnt[j][1]-jnt[j-1][1], l2 = jnt[j][2]-jnt[j-1][2];
                tmp = G[r*4+0]*l0 + G[r*4+1]*l1 + G[r*4+2]*l2 + G[r*4+3];
            }
        }
        __syncthreads();
        if (tid < 12) G[tid] = tmp;
        __syncthreads();
        if (tid < 12) {
            float aval = tmp;
            if (cc == 3)
                aval = tmp - (G[r*4+0]*jnt[j][0] + G[r*4+1]*jnt[j][1] + G[r*4+2]*jnt[j][2]);
            AHb[tid*64 + j] = (f16)aval;   // row m2 = b*16 + (r*4+cc), col j
        }
        __syncthreads();
    }
}

// ---------------- kernel 5: pose GEMM, swapped operands ----------------
// Block: 64 vcols (n0..n0+63) x 512 batches, K=512.
// A-frags (vcol-major) from LDS pd-tile; B-frags (batch) direct from PFH (L2).
// No barriers in the K-loop.
#define BTS 520   // LDS row stride (halves) for pd tile
__global__ __launch_bounds__(256, 2) void k_pose(
    const float* __restrict__ pd, const float* __restrict__ ed,
    const float* __restrict__ ws, const f16* __restrict__ PFH,
    f16* __restrict__ VPH)
{
    __shared__ f16 Bt[64*BTS];   // [c][k]; epilogue reuses as L[b][c] stride 65
    __shared__ float SDl[64];
    const int t = threadIdx.x;
    const int n0 = blockIdx.x * 64;
    const int w = t >> 6, lane = t & 63, l = lane & 15, q = lane >> 4;

    // ---- stage pd tile: f32 [k][n] -> f16 LDS [c][k], zero-padded ----
    {
        const int krow = t & 15, f = t >> 4;   // per instr: 16 k-rows x 4 cols(f4)
        const int nb = n0 + f*4;
        #pragma unroll 4
        for (int it = 0; it < 32; ++it) {
            int k = krow + it*16;
            float4 vv = make_float4(0.f, 0.f, 0.f, 0.f);
            if (k < 486) {
                if (nb + 3 < VC3) vv = *(const float4*)(pd + (size_t)k*VC3 + nb);
                else {
                    float* pv = (float*)&vv;
                    for (int e = 0; e < 4; ++e)
                        if (nb + e < VC3) pv[e] = pd[(size_t)k*VC3 + nb + e];
                }
            } else if (k < 496) {
                float* pv = (float*)&vv;
                for (int e = 0; e < 4; ++e)
                    if (nb + e < VC3) pv[e] = ed[(size_t)(nb + e)*10 + (k - 486)];
            }
            int c = f*4;
            Bt[(c+0)*BTS + k] = (f16)vv.x;
            Bt[(c+1)*BTS + k] = (f16)vv.y;
            Bt[(c+2)*BTS + k] = (f16)vv.z;
            Bt[(c+3)*BTS + k] = (f16)vv.w;
        }
    }
    if (t < 64) { int n = n0 + t; SDl[t] = (n < VC3) ? ws[SD_F + n] : 0.f; }
    __syncthreads();

    // ---- K loop: no barriers ----
    f32x4 acc[4][8];
    #pragma unroll
    for (int i = 0; i < 4; ++i)
        #pragma unroll
        for (int j = 0; j < 8; ++j) acc[i][j] = (f32x4)0.f;

    for (int kc = 0; kc < 16; ++kc) {
        f16x8 af[4], bf[8];
        #pragma unroll
        for (int mt = 0; mt < 4; ++mt)
            af[mt] = *(const f16x8*)&Bt[(mt*16 + l)*BTS + kc*32 + q*8];
        #pragma unroll
        for (int nt = 0; nt < 8; ++nt)
            bf[nt] = *(const f16x8*)&PFH[(size_t)(w*128 + nt*16 + l)*512 + kc*32 + q*8];
        #pragma unroll
        for (int mt = 0; mt < 4; ++mt)
            #pragma unroll
            for (int nt = 0; nt < 8; ++nt)
                acc[mt][nt] = __builtin_amdgcn_mfma_f32_16x16x32_f16(af[mt], bf[nt], acc[mt][nt], 0, 0, 0);
    }

    // ---- epilogue via LDS: lane holds D[c = mt*16+q*4+i][b = w*128+nt*16+l] ----
    __syncthreads();                 // all waves done reading Bt
    f16* L = Bt;                     // [b][c], stride 65 (511*65+63 = 33278 < 33280)
    #pragma unroll
    for (int mt = 0; mt < 4; ++mt)
        #pragma unroll
        for (int nt = 0; nt < 8; ++nt) {
            int b = w*128 + nt*16 + l;
            #pragma unroll
            for (int i = 0; i < 4; ++i) {
                int c = mt*16 + q*4 + i;
                L[b*65 + c] = (f16)(acc[mt][nt][i] + SDl[c]);
            }
        }
    __syncthreads();
    {
        const int c = t & 63, wv = t >> 6;
        const int n = n0 + c, v = n / 3, rem = n - 3*v;
        const size_t vcol = (size_t)v*4 + rem;
        for (int it = 0; it < 128; ++it) {
            int b = wv + 4*it;
            VPH[(size_t)b*VPROW + vcol] = L[b*65 + c];
        }
    }
}

// ---------------- kernel 6: LBS GEMM + epilogue ----------------
// Block: 64 verts x 512 m2-rows. A-frags direct from AH (L2); Bl = lbsw^T tile.
__global__ __launch_bounds__(256, 2) void k_lbs(
    const float* __restrict__ lw, const float* __restrict__ gt,
    const float* __restrict__ ws, const f16* __restrict__ AH,
    const f16* __restrict__ VPH, float* __restrict__ out)
{
    __shared__ f16 Bl[64*72];    // [v][j], stride 72
    const int t = threadIdx.x;
    const int n0 = blockIdx.x * 64;
    const int m0 = blockIdx.y * 512;
    const int w = t >> 6, lane = t & 63, l = lane & 15, q = lane >> 4;

    for (int idx = t; idx < 64*64; idx += 256) {
        int vl = idx >> 6, j = idx & 63;
        int v = n0 + vl;
        float val = (j < JN && v < VN) ? lw[(size_t)v*JN + j] : 0.f;
        Bl[vl*72 + j] = (f16)val;
    }
    __syncthreads();

    f32x4 acc[8][4];
    #pragma unroll
    for (int i = 0; i < 8; ++i)
        #pragma unroll
        for (int j = 0; j < 4; ++j) acc[i][j] = (f32x4)0.f;

    #pragma unroll
    for (int ks = 0; ks < 2; ++ks) {
        f16x8 af[8], bf[4];
        #pragma unroll
        for (int nt = 0; nt < 4; ++nt)
            bf[nt] = *(const f16x8*)&Bl[(nt*16 + l)*72 + ks*32 + q*8];
        #pragma unroll
        for (int mt = 0; mt < 8; ++mt)
            af[mt] = *(const f16x8*)&AH[(size_t)(m0 + w*128 + mt*16 + l)*64 + ks*32 + q*8];
        #pragma unroll
        for (int mt = 0; mt < 8; ++mt)
            #pragma unroll
            for (int nt = 0; nt < 4; ++nt)
                acc[mt][nt] = __builtin_amdgcn_mfma_f32_16x16x32_f16(af[mt], bf[nt], acc[mt][nt], 0, 0, 0);
    }

    // lane (l,q) reg i: D[m2 = m0 + w*128 + mt*16 + q*4 + i][v = n0 + nt*16 + l]
    //   => b = m0/16 + w*8 + mt, r = q, c = i
    float yoff = ws[Y_F];
    if (q < 3) {
        #pragma unroll
        for (int mt = 0; mt < 8; ++mt) {
            int b = (m0 >> 4) + w*8 + mt;
            float add = gt[b*3 + q] + (q == 1 ? yoff : 0.f);
            #pragma unroll
            for (int nt = 0; nt < 4; ++nt) {
                int v = n0 + nt*16 + l;
                if (v < VN) {
                    f16x4 vp = *(const f16x4*)(VPH + (size_t)b*VPROW + (size_t)v*4);
                    f32x4 T = acc[mt][nt];
                    out[((size_t)b*VN + v)*3 + q] =
                        T[0]*(float)vp[0] + T[1]*(float)vp[1] + T[2]*(float)vp[2] + T[3] + add;
                }
            }
        }
    }
}

extern "C" void kernel_launch(void* const* d_in, const int* in_sizes, int n_in,
                              void* d_out, int out_size, void* d_ws, size_t ws_size,
                              hipStream_t stream)
{
    const float* shape  = (const float*)d_in[0];
    const float* body   = (const float*)d_in[1];
    const float* hand   = (const float*)d_in[2];
    const float* head   = (const float*)d_in[3];
    const float* expr   = (const float*)d_in[4];
    const float* pelvis = (const float*)d_in[5];
    const float* gtrans = (const float*)d_in[6];
    const float* vt     = (const float*)d_in[7];
    const float* shdirs = (const float*)d_in[8];
    const float* exdirs = (const float*)d_in[9];
    const float* pdirs  = (const float*)d_in[10];
    const float* lbsw   = (const float*)d_in[11];
    const float* jreg   = (const float*)d_in[12];
    const float* hmean  = (const float*)d_in[13];
    float* wsf = (float*)d_ws;
    f16*   PFH = (f16*)((char*)d_ws + PFH_BYTE);
    f16*   AH  = (f16*)((char*)d_ws + AH_BYTE);
    f16*   VPH = (f16*)((char*)d_ws + VPH_BYTE);
    float* out = (float*)d_out;

    hipLaunchKernelGGL(k_sdirs, dim3((VC3 + 255)/256), dim3(256), 0, stream,
                       vt, shdirs, shape, wsf);
    hipLaunchKernelGGL(k_ymin,  dim3(1),    dim3(256), 0, stream, vt, wsf);
    hipLaunchKernelGGL(k_jreg,  dim3(JN*3), dim3(256), 0, stream, jreg, exdirs, wsf);
    hipLaunchKernelGGL(k_batch, dim3(BN),   dim3(64),  0, stream,
                       body, hand, head, expr, pelvis, hmean, wsf, PFH, AH);
    hipLaunchKernelGGL(k_pose,  dim3(NPAD/64), dim3(256), 0, stream,
                       pdirs, exdirs, wsf, PFH, VPH);
    hipLaunchKernelGGL(k_lbs,   dim3(VPADV/64, 8192/512), dim3(256), 0, stream,
                       lbsw, gtrans, wsf, AH, VPH, out);
}

// Round 5
// 312.617 us; speedup vs baseline: 2.9234x; 1.1558x over previous
//
#include <hip/hip_runtime.h>
#include <hip/hip_bf16.h>

// SMPL-X LBS forward. B=512, V=10475, J=55. f32 in/out; fp16 MFMA internally.
//
//  k_sdirs : s_dirs = v_template + shape.shapedirs
//  k_ymin  : y_offset
//  k_jreg  : Js = Jreg@s_dirs, JE = Jreg@exprdirs
//  k_lwT   : lwT f16 [10496][64] = lbs_weights^T-padded (j-contig per vert)
//  k_batch : Rodrigues -> PFH f16 [512 b][512 k], chain -> AH f16 [8192][64]
//  k_pose  : D[n][b] = pdT_tile(LDS) x PFH(direct L2); +s_dirs -> VPH2 f16 [b][31488]
//  k_lbs   : T = AH x lwT (both direct L2, no LDS/barriers); out = T.[vp;1]

typedef _Float16 f16;
typedef f16  f16x8 __attribute__((ext_vector_type(8)));
typedef f16  f16x4 __attribute__((ext_vector_type(4)));
typedef float f32x4 __attribute__((ext_vector_type(4)));

#define VN    10475
#define JN    55
#define BN    512
#define VC3   31425
#define NPAD  31488          // 492*64
#define VPADV 10496

// f32 ws region (float offsets):
#define SD_F  0              // s_dirs [VC3]
#define JS_F  31425          // [165]
#define JE_F  31590          // [1650]
#define Y_F   33240
// byte offsets:
#define PFH_BYTE  (160*1024)           // f16 [512][512]   = 512 KB
#define AH_BYTE   (768*1024)           // f16 [8192][64]   = 1 MB
#define VPH_BYTE  (2*1024*1024)        // f16 [512][31488] = 30.75 MB
#define LWT_BYTE  (34*1024*1024)       // f16 [10496][64]  = 1.3 MB

// ---------------- kernel 1 ----------------
__global__ void k_sdirs(const float* __restrict__ vt, const float* __restrict__ shapedirs,
                        const float* __restrict__ shape, float* __restrict__ ws)
{
    int i = blockIdx.x * 256 + threadIdx.x;
    if (i >= VC3) return;
    float acc = vt[i];
    const float* sd = shapedirs + (size_t)i * 10;
    #pragma unroll
    for (int s = 0; s < 10; ++s) acc += shape[s] * sd[s];
    ws[SD_F + i] = acc;
}

// ---------------- kernel 2 ----------------
__global__ void k_ymin(const float* __restrict__ vt, float* __restrict__ ws)
{
    __shared__ float red[256];
    int tid = threadIdx.x;
    float m = 3.0e38f;
    for (int v = tid; v < VN; v += 256) m = fminf(m, vt[v*3 + 1]);
    red[tid] = m;
    __syncthreads();
    for (int s = 128; s > 0; s >>= 1) {
        if (tid < s) red[tid] = fminf(red[tid], red[tid + s]);
        __syncthreads();
    }
    if (tid == 0) ws[Y_F] = -red[0];
}

// ---------------- kernel 3 ----------------
__global__ void k_jreg(const float* __restrict__ jr, const float* __restrict__ exprdirs,
                       float* __restrict__ ws)
{
    int j = blockIdx.x / 3, c = blockIdx.x % 3;
    int tid = threadIdx.x;
    const float* sdir = ws + SD_F;
    float acc[11];
    #pragma unroll
    for (int i = 0; i < 11; ++i) acc[i] = 0.f;
    for (int v = tid; v < VN; v += 256) {
        float w = jr[(size_t)j * VN + v];
        acc[10] += w * sdir[v*3 + c];
        const float* ed = exprdirs + (size_t)(v*3 + c) * 10;
        #pragma unroll
        for (int e = 0; e < 10; ++e) acc[e] += w * ed[e];
    }
    __shared__ float red[256];
    for (int i = 0; i < 11; ++i) {
        red[tid] = acc[i];
        __syncthreads();
        for (int s = 128; s > 0; s >>= 1) {
            if (tid < s) red[tid] += red[tid + s];
            __syncthreads();
        }
        if (tid == 0) {
            if (i == 10) ws[JS_F + j*3 + c] = red[0];
            else         ws[JE_F + (j*3 + c)*10 + i] = red[0];
        }
        __syncthreads();
    }
}

// ---------------- kernel 3b: lbs_weights -> f16 [v][64] j-contig ----------------
__global__ void k_lwT(const float* __restrict__ lw, f16* __restrict__ lwT)
{
    int t = threadIdx.x;
    int v  = blockIdx.x * 64 + (t >> 2);
    int jg = (t & 3) * 16;
    f16 tmp[16];
    #pragma unroll
    for (int jj = 0; jj < 16; ++jj) {
        int j = jg + jj;
        tmp[jj] = (f16)((v < VN && j < JN) ? lw[(size_t)v*JN + j] : 0.f);
    }
    *(f16x8*)&lwT[(size_t)v*64 + jg]     = *(f16x8*)&tmp[0];
    *(f16x8*)&lwT[(size_t)v*64 + jg + 8] = *(f16x8*)&tmp[8];
}

// ---------------- kernel 4: per-batch pose prep ----------------
__global__ void k_batch(const float* __restrict__ body, const float* __restrict__ hand,
                        const float* __restrict__ head, const float* __restrict__ expr,
                        const float* __restrict__ pelvis, const float* __restrict__ hand_mean,
                        const float* __restrict__ ws, f16* __restrict__ PFH,
                        f16* __restrict__ AH)
{
    int b = blockIdx.x, tid = threadIdx.x;
    __shared__ float rot[JN][9];
    __shared__ float jnt[JN][3];
    __shared__ float G[12];

    f16* AHb = AH + (size_t)b * 1024;
    #pragma unroll
    for (int i = 0; i < 16; ++i) AHb[tid + i*64] = (f16)0.f;

    if (tid < JN) {
        int j = tid;
        float r0, r1, r2;
        if (j == 0) {
            r0 = pelvis[b*3+0]; r1 = pelvis[b*3+1]; r2 = pelvis[b*3+2];
        } else if (j <= 21) {
            int o = b*63 + (j-1)*3;
            r0 = body[o]; r1 = body[o+1]; r2 = body[o+2];
        } else if (j <= 24) {
            int o = b*9 + (j-22)*3;
            r0 = head[o]; r1 = head[o+1]; r2 = head[o+2];
        } else {
            int h = (j-25)*3;
            r0 = hand[b*90+h+0] + hand_mean[h+0];
            r1 = hand[b*90+h+1] + hand_mean[h+1];
            r2 = hand[b*90+h+2] + hand_mean[h+2];
        }
        float a2  = r0*r0 + r1*r1 + r2*r2 + 1e-12f;
        float ang = sqrtf(a2);
        float inv = 1.0f / ang;
        float kx = r0*inv, ky = r1*inv, kz = r2*inv;
        float s = sinf(ang), c = cosf(ang), ic = 1.0f - c;
        rot[j][0] = c + ic*kx*kx;    rot[j][1] = ic*kx*ky - s*kz; rot[j][2] = ic*kx*kz + s*ky;
        rot[j][3] = ic*kx*ky + s*kz; rot[j][4] = c + ic*ky*ky;    rot[j][5] = ic*ky*kz - s*kx;
        rot[j][6] = ic*kx*kz - s*ky; rot[j][7] = ic*ky*kz + s*kx; rot[j][8] = c + ic*kz*kz;
        #pragma unroll
        for (int cc = 0; cc < 3; ++cc) {
            float acc = ws[JS_F + j*3 + cc];
            #pragma unroll
            for (int e = 0; e < 10; ++e)
                acc += expr[b*10 + e] * ws[JE_F + (j*3 + cc)*10 + e];
            jnt[j][cc] = acc;
        }
    }
    __syncthreads();

    // PFH row b: [0..486) pose_feature | [486..496) expr | [496..512) zero
    #pragma unroll
    for (int i = 0; i < 8; ++i) {
        int k = tid + i*64;
        float val = 0.f;
        if (k < 486) {
            int jj = k/9 + 1, ii = k%9;
            float d = (ii == 0 || ii == 4 || ii == 8) ? 1.0f : 0.0f;
            val = rot[jj][ii] - d;
        } else if (k < 496) {
            val = expr[b*10 + (k-486)];
        }
        PFH[(size_t)b*512 + k] = (f16)val;
    }

    int r = tid >> 2, cc = tid & 3;
    if (tid < 12) G[tid] = (cc < 3) ? rot[0][r*3 + cc] : jnt[0][r];
    __syncthreads();
    for (int j = 0; j < JN; ++j) {
        float tmp = 0.f;
        if (tid < 12) {
            if (j == 0) tmp = G[tid];
            else if (cc < 3)
                tmp = G[r*4+0]*rot[j][cc] + G[r*4+1]*rot[j][3+cc] + G[r*4+2]*rot[j][6+cc];
            else {
                float l0 = jnt[j][0]-jnt[j-1][0], l1 = jnt[j][1]-jnt[j-1][1], l2 = jnt[j][2]-jnt[j-1][2];
                tmp = G[r*4+0]*l0 + G[r*4+1]*l1 + G[r*4+2]*l2 + G[r*4+3];
            }
        }
        __syncthreads();
        if (tid < 12) G[tid] = tmp;
        __syncthreads();
        if (tid < 12) {
            float aval = tmp;
            if (cc == 3)
                aval = tmp - (G[r*4+0]*jnt[j][0] + G[r*4+1]*jnt[j][1] + G[r*4+2]*jnt[j][2]);
            AHb[tid*64 + j] = (f16)aval;   // row m2 = b*16 + (r*4+cc), col j
        }
        __syncthreads();
    }
}

// ---------------- kernel 5: pose GEMM, swapped operands ----------------
// Block: 64 n-cols x 512 batches, K=512. A-frags from LDS pd-tile; B-frags
// direct from PFH (L2). No barriers in K-loop. Epilogue: LDS transpose ->
// f16x4 coalesced stores into VPH2[b][n] (unpadded, width 31488).
#define BTS 520                     // pd tile row stride (halves)
#define LTS 72                      // epilogue L[b][c] stride (halves)
__global__ __launch_bounds__(256, 2) void k_pose(
    const float* __restrict__ pd, const float* __restrict__ ed,
    const float* __restrict__ ws, const f16* __restrict__ PFH,
    f16* __restrict__ VPH2)
{
    __shared__ f16 SH[BN*LTS];      // 36864 halves; pd-tile needs 64*520=33280
    __shared__ float SDl[64];
    const int t = threadIdx.x;
    const int n0 = blockIdx.x * 64;
    const int w = t >> 6, lane = t & 63, l = lane & 15, q = lane >> 4;
    f16* Bt = SH;

    {   // stage pd tile: f32 [k][n] -> f16 LDS [c][k]
        const int krow = t & 15, f = t >> 4;
        const int nb = n0 + f*4;
        #pragma unroll 4
        for (int it = 0; it < 32; ++it) {
            int k = krow + it*16;
            float4 vv = make_float4(0.f, 0.f, 0.f, 0.f);
            if (k < 486) {
                if (nb + 3 < VC3) vv = *(const float4*)(pd + (size_t)k*VC3 + nb);
                else {
                    float* pv = (float*)&vv;
                    for (int e = 0; e < 4; ++e)
                        if (nb + e < VC3) pv[e] = pd[(size_t)k*VC3 + nb + e];
                }
            } else if (k < 496) {
                float* pv = (float*)&vv;
                for (int e = 0; e < 4; ++e)
                    if (nb + e < VC3) pv[e] = ed[(size_t)(nb + e)*10 + (k - 486)];
            }
            int c = f*4;
            Bt[(c+0)*BTS + k] = (f16)vv.x;
            Bt[(c+1)*BTS + k] = (f16)vv.y;
            Bt[(c+2)*BTS + k] = (f16)vv.z;
            Bt[(c+3)*BTS + k] = (f16)vv.w;
        }
    }
    if (t < 64) { int n = n0 + t; SDl[t] = (n < VC3) ? ws[SD_F + n] : 0.f; }
    __syncthreads();

    f32x4 acc[4][8];
    #pragma unroll
    for (int i = 0; i < 4; ++i)
        #pragma unroll
        for (int j = 0; j < 8; ++j) acc[i][j] = (f32x4)0.f;

    for (int kc = 0; kc < 16; ++kc) {
        f16x8 af[4], bf[8];
        #pragma unroll
        for (int mt = 0; mt < 4; ++mt)
            af[mt] = *(const f16x8*)&Bt[(mt*16 + l)*BTS + kc*32 + q*8];
        #pragma unroll
        for (int nt = 0; nt < 8; ++nt)
            bf[nt] = *(const f16x8*)&PFH[(size_t)(w*128 + nt*16 + l)*512 + kc*32 + q*8];
        #pragma unroll
        for (int mt = 0; mt < 4; ++mt)
            #pragma unroll
            for (int nt = 0; nt < 8; ++nt)
                acc[mt][nt] = __builtin_amdgcn_mfma_f32_16x16x32_f16(af[mt], bf[nt], acc[mt][nt], 0, 0, 0);
    }

    // epilogue: lane holds D[c = mt*16+q*4+i][b = w*128+nt*16+l]
    __syncthreads();                 // waves done reading Bt
    f16* L = SH;                     // [b][c] stride LTS
    #pragma unroll
    for (int mt = 0; mt < 4; ++mt)
        #pragma unroll
        for (int nt = 0; nt < 8; ++nt) {
            int b = w*128 + nt*16 + l;
            f16 pack[4];
            #pragma unroll
            for (int i = 0; i < 4; ++i) {
                int c = mt*16 + q*4 + i;
                pack[i] = (f16)(acc[mt][nt][i] + SDl[c]);
            }
            *(f16x4*)&L[b*LTS + mt*16 + q*4] = *(f16x4*)&pack[0];
        }
    __syncthreads();
    {   // coalesced f16x4 stores: 16 threads cover 64 cols, 16 b per pass
        const int c4 = (t & 15) * 4, bq = t >> 4;
        #pragma unroll 4
        for (int it = 0; it < 32; ++it) {
            int b = bq + 16*it;
            *(f16x4*)&VPH2[(size_t)b*NPAD + n0 + c4] = *(const f16x4*)&L[b*LTS + c4];
        }
    }
}

// ---------------- kernel 6: LBS GEMM + epilogue (no LDS, no barriers) ----------
// Block: 64 verts x 256 m2-rows (wave owns 64 m2). A-frags direct from AH,
// B-frags direct from lwT (both L2-resident).
__global__ __launch_bounds__(256) void k_lbs(
    const float* __restrict__ gt, const float* __restrict__ ws,
    const f16* __restrict__ AH, const f16* __restrict__ lwT,
    const f16* __restrict__ VPH2, float* __restrict__ out)
{
    const int t = threadIdx.x;
    const int n0 = blockIdx.x * 64;
    const int m0 = blockIdx.y * 256;
    const int w = t >> 6, lane = t & 63, l = lane & 15, q = lane >> 4;

    f32x4 acc[4][4];
    #pragma unroll
    for (int i = 0; i < 4; ++i)
        #pragma unroll
        for (int j = 0; j < 4; ++j) acc[i][j] = (f32x4)0.f;

    #pragma unroll
    for (int ks = 0; ks < 2; ++ks) {
        f16x8 af[4], bf[4];
        #pragma unroll
        for (int nt = 0; nt < 4; ++nt)
            bf[nt] = *(const f16x8*)&lwT[(size_t)(n0 + nt*16 + l)*64 + ks*32 + q*8];
        #pragma unroll
        for (int mt = 0; mt < 4; ++mt)
            af[mt] = *(const f16x8*)&AH[(size_t)(m0 + w*64 + mt*16 + l)*64 + ks*32 + q*8];
        #pragma unroll
        for (int mt = 0; mt < 4; ++mt)
            #pragma unroll
            for (int nt = 0; nt < 4; ++nt)
                acc[mt][nt] = __builtin_amdgcn_mfma_f32_16x16x32_f16(af[mt], bf[nt], acc[mt][nt], 0, 0, 0);
    }

    // lane (l,q) reg i: D[m2 = m0 + w*64 + mt*16 + q*4 + i][v = n0 + nt*16 + l]
    //   => b = m0/16 + w*4 + mt, r = q, c = i
    float yoff = ws[Y_F];
    if (q < 3) {
        #pragma unroll
        for (int mt = 0; mt < 4; ++mt) {
            int b = (m0 >> 4) + w*4 + mt;
            float add = gt[b*3 + q] + (q == 1 ? yoff : 0.f);
            const f16* vb = VPH2 + (size_t)b*NPAD;
            #pragma unroll
            for (int nt = 0; nt < 4; ++nt) {
                int v = n0 + nt*16 + l;
                if (v < VN) {
                    float vx = (float)vb[3*v], vy = (float)vb[3*v+1], vz = (float)vb[3*v+2];
                    f32x4 T = acc[mt][nt];
                    out[((size_t)b*VN + v)*3 + q] = T[0]*vx + T[1]*vy + T[2]*vz + T[3] + add;
                }
            }
        }
    }
}

extern "C" void kernel_launch(void* const* d_in, const int* in_sizes, int n_in,
                              void* d_out, int out_size, void* d_ws, size_t ws_size,
                              hipStream_t stream)
{
    const float* shape  = (const float*)d_in[0];
    const float* body   = (const float*)d_in[1];
    const float* hand   = (const float*)d_in[2];
    const float* head   = (const float*)d_in[3];
    const float* expr   = (const float*)d_in[4];
    const float* pelvis = (const float*)d_in[5];
    const float* gtrans = (const float*)d_in[6];
    const float* vt     = (const float*)d_in[7];
    const float* shdirs = (const float*)d_in[8];
    const float* exdirs = (const float*)d_in[9];
    const float* pdirs  = (const float*)d_in[10];
    const float* lbsw   = (const float*)d_in[11];
    const float* jreg   = (const float*)d_in[12];
    const float* hmean  = (const float*)d_in[13];
    float* wsf  = (float*)d_ws;
    f16*   PFH  = (f16*)((char*)d_ws + PFH_BYTE);
    f16*   AH   = (f16*)((char*)d_ws + AH_BYTE);
    f16*   VPH2 = (f16*)((char*)d_ws + VPH_BYTE);
    f16*   lwT  = (f16*)((char*)d_ws + LWT_BYTE);
    float* out  = (float*)d_out;

    hipLaunchKernelGGL(k_sdirs, dim3((VC3 + 255)/256), dim3(256), 0, stream,
                       vt, shdirs, shape, wsf);
    hipLaunchKernelGGL(k_ymin,  dim3(1),    dim3(256), 0, stream, vt, wsf);
    hipLaunchKernelGGL(k_jreg,  dim3(JN*3), dim3(256), 0, stream, jreg, exdirs, wsf);
    hipLaunchKernelGGL(k_lwT,   dim3(VPADV/64), dim3(256), 0, stream, lbsw, lwT);
    hipLaunchKernelGGL(k_batch, dim3(BN),   dim3(64),  0, stream,
                       body, hand, head, expr, pelvis, hmean, wsf, PFH, AH);
    hipLaunchKernelGGL(k_pose,  dim3(NPAD/64), dim3(256), 0, stream,
                       pdirs, exdirs, wsf, PFH, VPH2);
    hipLaunchKernelGGL(k_lbs,   dim3(VPADV/64, 8192/256), dim3(256), 0, stream,
                       gtrans, wsf, AH, lwT, VPH2, out);
}